// Round 15
// baseline (124.534 us; speedup 1.0000x reference)
//
#include <hip/hip_runtime.h>
#include <math.h>

// CRF loss: B=256, L=256, T=50.
// R15: UNIFORM chunked matrix-product scan — no vector chains at all.
//   normalizer = v0 . M1..M255 . 1,  M_l = mask_l ? E2*diag(eh_l) : I,
//   v0 = exp2(emit_0/ln2).
//   Scan: 2048 blocks (b, c=0..7) x 256 thr (4 waves = 4 column slabs):
//     chunk c covers steps l = max(1,32c) .. 32c+31 (c=0 skips l=0).
//     Y <- diag(eh_l)*E2^T*Y per step: constant A-frags (E2^T) with the sigma
//     K-permutation (R11-verified) -> C-layout output repacks into next B-frags
//     lane-locally; per-slab renorm by own diagonal pivot; S_w per slab.
//   Combine (256 x 64): x = eh0; 8x (slab-scale, x <- T~_c x, renorm); out =
//     ln2*(Ssum + log2(sum x)) - gold.
//   __launch_bounds__(256,1): R14's VGPR_Count=52 forced the constant A-frags
//   into AGPRs with per-step v_accvgpr shuttles (~32 VALU/step); uncap VGPRs.

#define TAGS 50
#define LEN 256
#define NB 256
#define NCH 8
#define CST 32
#define INV_LN2 1.4426950408889634f
#define LN2 0.6931471805599453f

typedef __attribute__((ext_vector_type(8))) short bf16x8;
typedef __attribute__((ext_vector_type(4))) float f32x4;

#if __has_builtin(__builtin_amdgcn_exp2f)
#define EXP2F(x) __builtin_amdgcn_exp2f(x)
#else
#define EXP2F(x) exp2f(x)
#endif
#if __has_builtin(__builtin_amdgcn_logf)
#define LOG2F(x) __builtin_amdgcn_logf(x)
#else
#define LOG2F(x) log2f(x)
#endif
#if __has_builtin(__builtin_amdgcn_rcpf)
#define RCPF(x) __builtin_amdgcn_rcpf(x)
#else
#define RCPF(x) (1.0f / (x))
#endif

__device__ __forceinline__ float readlane_f(float v, int srclane) {
  return __builtin_bit_cast(float,
      __builtin_amdgcn_readlane(__builtin_bit_cast(int, v), srclane));
}

__device__ __forceinline__ int bfpack(float lo, float hi) {
  unsigned lb = __builtin_bit_cast(unsigned, lo) + 0x8000u;
  unsigned hb = __builtin_bit_cast(unsigned, hi) + 0x8000u;
#if __has_builtin(__builtin_amdgcn_perm)
  return (int)__builtin_amdgcn_perm(hb, lb, 0x07060302u);
#else
  return (int)((hb & 0xFFFF0000u) | (lb >> 16));
#endif
}

union U8 { int i[4]; bf16x8 v; };

// ws layout (floats): per-(b,c) slab scales then T matrices
#define WS_SC(b,c) ((((b) * NCH) + (c)) * 4)
#define WS_T(b,c)  (NB * NCH * 4 + (((b) * NCH) + (c)) * 4096)

__global__ __launch_bounds__(256, 1) void crf_scan_kernel(
    const float* __restrict__ feats,   // (B, L, T)
    const float* __restrict__ trans,   // (T, T)
    const int*   __restrict__ mask,    // (B, L)
    float*       __restrict__ ws)
{
  const int bid  = blockIdx.x;
  const int tid  = threadIdx.x;
  const int w    = tid >> 6;                        // wave = column slab
  const int lane = tid & 63;
  const int q    = (tid >> 4) & 3;
  const int n    = tid & 15;
  const f32x4 zero4 = {0.0f, 0.0f, 0.0f, 0.0f};

  const int b  = bid >> 3;
  const int c  = bid & 7;
  const int l0 = c * CST;
  const int lstart = (c == 0) ? 1 : 0;

  __shared__ __align__(16) float eh[CST * 52 + 16]; // exp2(emit/ln2), stride 52
  __shared__ int ml[CST];

  for (int i = tid; i < CST * 52 + 16; i += 256) eh[i] = 1.0f;  // pad-safe
  __syncthreads();

  const float* fbc = feats + ((size_t)b * LEN + l0) * TAGS;
  {
    const float4* fv = (const float4*)fbc;          // 400 float4
    for (int i = tid; i < (CST * TAGS) / 4; i += 256) {
      const float4 v4 = fv[i];
      const int g = i * 4;
#pragma unroll
      for (int e = 0; e < 4; ++e) {
        const int gg = g + e;
        const int row = gg / TAGS;
        const int col = gg - row * TAGS;
        const float val = (e == 0) ? v4.x : (e == 1) ? v4.y : (e == 2) ? v4.z : v4.w;
        eh[row * 52 + col] = EXP2F(val * INV_LN2);
      }
    }
    if (tid < CST) ml[tid] = mask[b * LEN + l0 + tid];
  }

  // Constant A-frags: E2^T, sigma slot (c2,q,j) -> row 32c2+16(j>>2)+4q+2((j>>1)&1)+(j&1)
  U8 Afr[4][2];
#pragma unroll
  for (int tm = 0; tm < 4; ++tm)
#pragma unroll
    for (int c2 = 0; c2 < 2; ++c2)
#pragma unroll
      for (int rr = 0; rr < 4; ++rr) {
        const int m = 16 * tm + n;
        const int kr = 32 * c2 + 16 * (rr >> 1) + 4 * q + 2 * (rr & 1);
        const float e0 = (m < TAGS && kr < TAGS)
            ? EXP2F(trans[kr * TAGS + m] * INV_LN2) : 0.0f;
        const float e1 = (m < TAGS && kr + 1 < TAGS)
            ? EXP2F(trans[(kr + 1) * TAGS + m] * INV_LN2) : 0.0f;
        Afr[tm][c2].i[rr] = bfpack(e0, e1);
      }

  __syncthreads();

  // Y = basis columns of slab w: d[tm][e] = Y[16tm+4q+e][16w+n]
  f32x4 d[4];
#pragma unroll
  for (int tm = 0; tm < 4; ++tm)
#pragma unroll
    for (int e = 0; e < 4; ++e)
      d[tm][e] = (tm == w && (4 * q + e) == n) ? 1.0f : 0.0f;

  float S = 0.0f;

  for (int l = lstart; l < CST; ++l) {
    if (ml[l] > 0) {
      // pivot Y[16w][16w] -> d[w][0] at (q=0,n=0) = lane 0 of this wave
      float pvt = d[0][0];
      pvt = (w == 1) ? d[1][0] : pvt;
      pvt = (w == 2) ? d[2][0] : pvt;
      pvt = (w == 3) ? d[3][0] : pvt;
      const float cc = readlane_f(pvt, 0);          // > 0
      const float rv = RCPF(cc);
      const f32x4 rv4 = {rv, rv, rv, rv};

      // lane-local sigma repack -> B-frags
      U8 B0, B1;
      B0.i[0] = bfpack(d[0][0], d[0][1]);
      B0.i[1] = bfpack(d[0][2], d[0][3]);
      B0.i[2] = bfpack(d[1][0], d[1][1]);
      B0.i[3] = bfpack(d[1][2], d[1][3]);
      B1.i[0] = bfpack(d[2][0], d[2][1]);
      B1.i[1] = bfpack(d[2][2], d[2][3]);
      B1.i[2] = bfpack(d[3][0], d[3][1]);
      B1.i[3] = bfpack(d[3][2], d[3][3]);

      // 8 MFMAs (4 tm x 2 K-chunks), vector scale
#pragma unroll
      for (int tm = 0; tm < 4; ++tm) {
        f32x4 acc = __builtin_amdgcn_mfma_f32_16x16x32_bf16(
            Afr[tm][0].v, B0.v, zero4, 0, 0, 0);
        acc = __builtin_amdgcn_mfma_f32_16x16x32_bf16(
            Afr[tm][1].v, B1.v, acc, 0, 0, 0);
        const f32x4 er = *(const f32x4*)&eh[l * 52 + 16 * tm + 4 * q];
        d[tm] = acc * (er * rv4);
      }
      S += LOG2F(cc);
    }
  }

  // Store slab col-major: T~[row][col] at col*64+row.
  float* tw = ws + WS_T(b, c) + (16 * w + n) * 64;
#pragma unroll
  for (int tm = 0; tm < 4; ++tm)
    *(f32x4*)&tw[16 * tm + 4 * q] = d[tm];
  if (lane == 0) ws[WS_SC(b, c) + w] = S;
}

__global__ __launch_bounds__(64) void crf_combine_kernel(
    const float* __restrict__ feats,   // (B, L, T)
    const float* __restrict__ trans,   // (T, T)
    const int*   __restrict__ tags,    // (B, L)
    const int*   __restrict__ mask,    // (B, L)
    const float* __restrict__ ws,
    float*       __restrict__ out)     // (B,)
{
  const int b = blockIdx.x;
  const int lane = threadIdx.x;

  // x = v0 = exp2(emit_0/ln2), pads 0.
  float x = (lane < TAGS)
      ? EXP2F(feats[(size_t)b * (LEN * TAGS) + lane] * INV_LN2) : 0.0f;
  float Ssum = 0.0f;

  for (int c = 0; c < NCH; ++c) {
    // Per-slab scale correction: true T col j = T~ col j * 2^{S_w(j)}
    const float sw = ws[WS_SC(b, c) + (lane >> 4)];
    float m1 = fmaxf(sw, __shfl_xor(sw, 16, 64));
    const float smax = fmaxf(m1, __shfl_xor(m1, 32, 64));
    x *= EXP2F(sw - smax);

    const float* Tb = ws + WS_T(b, c) + lane;
    float a0 = 0.0f, a1 = 0.0f, a2 = 0.0f, a3 = 0.0f;
#pragma unroll
    for (int i = 0; i < 64; i += 4) {
      a0 = fmaf(Tb[(i + 0) * 64], readlane_f(x, i + 0), a0);
      a1 = fmaf(Tb[(i + 1) * 64], readlane_f(x, i + 1), a1);
      a2 = fmaf(Tb[(i + 2) * 64], readlane_f(x, i + 2), a2);
      a3 = fmaf(Tb[(i + 3) * 64], readlane_f(x, i + 3), a3);
    }
    const float acc = (a0 + a1) + (a2 + a3);
    const float cc = readlane_f(acc, 0);              // > 0
    x = acc * RCPF(cc);
    Ssum += smax + LOG2F(cc);
  }

  // normalizer: dot with ones (pads of x are 0)
  float s = x;
#pragma unroll
  for (int off = 32; off; off >>= 1) s += __shfl_xor(s, off, 64);

  // gold score
  const float* fb = feats + (size_t)b * (LEN * TAGS);
  const int*   tb = tags + b * LEN;
  const int*   mb = mask + b * LEN;
  float gp = 0.0f;
#pragma unroll
  for (int k = 0; k < 4; ++k) {
    const int p = lane + 64 * k;
    const int tg = tb[p];
    if (mb[p] > 0) {
      float vv = fb[p * TAGS + tg];
      if (p >= 1) vv += trans[tb[p - 1] * TAGS + tg];
      gp += vv;
    }
  }
#pragma unroll
  for (int off = 32; off; off >>= 1) gp += __shfl_xor(gp, off, 64);

  if (lane == 0) {
    out[b] = LN2 * (Ssum + LOG2F(s)) - gp;
  }
}

extern "C" void kernel_launch(void* const* d_in, const int* in_sizes, int n_in,
                              void* d_out, int out_size, void* d_ws, size_t ws_size,
                              hipStream_t stream) {
  const float* feats = (const float*)d_in[0];
  const float* trans = (const float*)d_in[1];
  const int*   tags  = (const int*)d_in[2];
  const int*   mask  = (const int*)d_in[3];
  float* out = (float*)d_out;
  float* ws  = (float*)d_ws;   // ~33.6 MB used

  crf_scan_kernel<<<NB * NCH, 256, 0, stream>>>(feats, trans, mask, ws);
  crf_combine_kernel<<<NB, 64, 0, stream>>>(feats, trans, tags, mask, ws, out);
}